// Round 1
// baseline (12486.558 us; speedup 1.0000x reference)
//
#include <hip/hip_runtime.h>
#include <hip/hip_bf16.h>
#include <stdint.h>

// LSTM forward, B=64 T=512 D=512 H=512, return_sequences.
// Design: single persistent kernel, 4 batch-groups x 8 column-slices = 32 blocks
// (all co-resident on 256 CUs). Per step: fused x@W (bf16 MFMA, A cvt'd from fp32)
// + flag-synced h@U (h published as bf16 hi/lo pair) + gates. Weights pre-transposed
// to bf16 [n][k] once per call. Flags zeroed via hipMemsetAsync each call.

#define Bdim 64
#define Tdim 512
#define Ddim 512
#define Hdim 512
#define G4H  2048

#define NG 4   // batch groups (16 rows each, MFMA M=16)
#define NS 8   // slices per group (64 h-cols each)

typedef __bf16 bf16_t;
typedef __bf16 bf16x8 __attribute__((ext_vector_type(8)));
typedef float  f32x4  __attribute__((ext_vector_type(4)));

__device__ __forceinline__ bf16_t to_bf16(float f) { return (bf16_t)f; }

__device__ __forceinline__ float sigmoid_f(float x) {
  return 1.0f / (1.0f + __expf(-x));
}
__device__ __forceinline__ float tanh_f(float x) {
  // tanh(x) = 1 - 2/(exp(2x)+1); stable at both tails (inf -> 1, 0 -> -1)
  return 1.0f - 2.0f / (__expf(2.0f * x) + 1.0f);
}

// src [512][2048] fp32  ->  dst [2048][512] bf16 (transposed)
__global__ void transpose_bf16_512x2048(const float* __restrict__ src,
                                        bf16_t* __restrict__ dst) {
  __shared__ bf16_t tile[64][72];  // padded
  int c0 = blockIdx.x * 64;  // src col (n)
  int r0 = blockIdx.y * 64;  // src row (k)
  int tx = threadIdx.x & 63;
  int ty = threadIdx.x >> 6;  // 0..3
#pragma unroll
  for (int i = 0; i < 64; i += 4) {
    tile[ty + i][tx] = to_bf16(src[(size_t)(r0 + ty + i) * G4H + c0 + tx]);
  }
  __syncthreads();
#pragma unroll
  for (int i = 0; i < 64; i += 4) {
    dst[(size_t)(c0 + ty + i) * Ddim + r0 + tx] = tile[tx][ty + i];
  }
}

__launch_bounds__(256, 1)
__global__ void lstm_fused(const float* __restrict__ x,     // [B][T][D]
                           const bf16_t* __restrict__ Wt,   // [2048][512]
                           const bf16_t* __restrict__ Ut,   // [2048][512]
                           const float* __restrict__ bias,  // [2048]
                           float* __restrict__ out,         // [B][T][H]
                           bf16_t* __restrict__ hbuf,       // [2 parity][2 hilo][B][H]
                           unsigned* __restrict__ flags) {  // [NG*NS] padded x32
  const int blk  = blockIdx.x;
  const int g    = blk >> 3;       // batch group
  const int s    = blk & 7;        // column slice
  const int wv   = threadIdx.x >> 6;
  const int lane = threadIdx.x & 63;
  const int l15  = lane & 15;
  const int l4   = lane >> 4;
  const int b0   = g * 16;
  const int hc0  = s * 64 + wv * 16;  // this wave's 16 h-cols

  // bias per gate for this lane's output column (same for all 4 C rows)
  float bg[4];
#pragma unroll
  for (int G = 0; G < 4; ++G) bg[G] = bias[G * Hdim + hc0 + l15];

  // B-frag base pointers (already include l4*8 k-offset within 32-wide chunk)
  const bf16_t* wrow[4];
  const bf16_t* urow[4];
#pragma unroll
  for (int G = 0; G < 4; ++G) {
    int zc = G * Hdim + hc0 + l15;
    wrow[G] = Wt + (size_t)zc * Ddim + l4 * 8;
    urow[G] = Ut + (size_t)zc * Ddim + l4 * 8;
  }

  // A-frag base for x: row = b0+l15 (M index), k offset l4*8
  const float* xrow = x + (size_t)(b0 + l15) * Tdim * Ddim + l4 * 8;
  const int crow = b0 + l4 * 4;  // C-layout batch row base (+r)

  f32x4 cstate = {0.f, 0.f, 0.f, 0.f};
  bool dead = false;  // deadlock safety valve (never expected to trip)

  for (int t = 0; t < Tdim; ++t) {
    f32x4 acc[4];
#pragma unroll
    for (int G = 0; G < 4; ++G) acc[G] = (f32x4){bg[G], bg[G], bg[G], bg[G]};

    // ---------- x_t @ W (independent of peers; runs before the wait) ----------
    const float* xp = xrow + (size_t)t * Ddim;
#pragma unroll 4
    for (int kk = 0; kk < 16; ++kk) {
      f32x4 xa = *(const f32x4*)(xp + kk * 32);
      f32x4 xb = *(const f32x4*)(xp + kk * 32 + 4);
      bf16x8 a;
#pragma unroll
      for (int j = 0; j < 4; ++j) {
        a[j]     = to_bf16(xa[j]);
        a[j + 4] = to_bf16(xb[j]);
      }
#pragma unroll
      for (int G = 0; G < 4; ++G) {
        bf16x8 b = *(const bf16x8*)(wrow[G] + kk * 32);
        acc[G] = __builtin_amdgcn_mfma_f32_16x16x32_bf16(a, b, acc[G], 0, 0, 0);
      }
    }

    if (t > 0) {
      // ---------- wait: all 8 slices of h_{t-1} published (stamp >= t) ----------
      if (!dead) {
        const unsigned* fp = flags + (size_t)(g * NS + (lane & 7)) * 32;
        int guard = 0;
        for (;;) {
          unsigned v = __hip_atomic_load(fp, __ATOMIC_ACQUIRE,
                                         __HIP_MEMORY_SCOPE_AGENT);
          if (__all((int)(v >= (unsigned)t))) break;
          if (++guard > 4000000) { dead = true; break; }
        }
      }
      // ---------- h_{t-1} @ U (hi + lo bf16 pair) ----------
      const bf16_t* hb  = hbuf + (size_t)(((t - 1) & 1) * 2) * Bdim * Hdim;
      const bf16_t* hhi = hb + (size_t)(b0 + l15) * Hdim + l4 * 8;
      const bf16_t* hlo = hhi + (size_t)Bdim * Hdim;
#pragma unroll 2
      for (int kk = 0; kk < 16; ++kk) {
        bf16x8 ah = *(const bf16x8*)(hhi + kk * 32);
        bf16x8 al = *(const bf16x8*)(hlo + kk * 32);
#pragma unroll
        for (int G = 0; G < 4; ++G) {
          bf16x8 b = *(const bf16x8*)(urow[G] + kk * 32);
          acc[G] = __builtin_amdgcn_mfma_f32_16x16x32_bf16(ah, b, acc[G], 0, 0, 0);
          acc[G] = __builtin_amdgcn_mfma_f32_16x16x32_bf16(al, b, acc[G], 0, 0, 0);
        }
      }
    }

    // ---------- gates + state update + publish ----------
    bf16_t* hw = hbuf + (size_t)((t & 1) * 2) * Bdim * Hdim;
#pragma unroll
    for (int r = 0; r < 4; ++r) {
      float ig = sigmoid_f(acc[0][r]);
      float fg = sigmoid_f(acc[1][r]);
      float ct = tanh_f(acc[2][r]);
      float og = sigmoid_f(acc[3][r]);
      float cn = tanh_f(fg * cstate[r] + ig * ct);  // module carries ACTIVATED cell
      cstate[r] = cn;
      float h = og * cn;
      int br = crow + r;
      out[((size_t)br * Tdim + t) * Hdim + hc0 + l15] = h;
      bf16_t hh = to_bf16(h);
      bf16_t hl = to_bf16(h - (float)hh);
      hw[(size_t)br * Hdim + hc0 + l15] = hh;
      hw[(size_t)Bdim * Hdim + (size_t)br * Hdim + hc0 + l15] = hl;
    }
    __syncthreads();
    if (threadIdx.x == 0) {
      __hip_atomic_store(flags + (size_t)(g * NS + s) * 32, (unsigned)(t + 1),
                         __ATOMIC_RELEASE, __HIP_MEMORY_SCOPE_AGENT);
    }
  }
}

extern "C" void kernel_launch(void* const* d_in, const int* in_sizes, int n_in,
                              void* d_out, int out_size, void* d_ws, size_t ws_size,
                              hipStream_t stream) {
  const float* x    = (const float*)d_in[0];
  const float* W    = (const float*)d_in[1];
  const float* U    = (const float*)d_in[2];
  const float* bias = (const float*)d_in[3];
  float* out = (float*)d_out;

  unsigned char* ws = (unsigned char*)d_ws;
  // layout: flags 4 KB | hbuf 256 KB | Wt 2 MB | Ut 2 MB   (total ~4.26 MB)
  unsigned* flags = (unsigned*)ws;
  bf16_t* hbuf = (bf16_t*)(ws + 4096);
  bf16_t* Wt   = (bf16_t*)(ws + 4096 + 2 * 2 * Bdim * Hdim * 2);
  bf16_t* Ut   = Wt + (size_t)G4H * Ddim;

  hipMemsetAsync(flags, 0, 4096, stream);

  dim3 tgrid(G4H / 64, Ddim / 64);
  transpose_bf16_512x2048<<<tgrid, 256, 0, stream>>>(W, Wt);
  transpose_bf16_512x2048<<<tgrid, 256, 0, stream>>>(U, Ut);

  lstm_fused<<<NG * NS, 256, 0, stream>>>(x, Wt, Ut, bias, out, hbuf, flags);
}

// Round 2
// 5062.663 us; speedup vs baseline: 2.4664x; 2.4664x over previous
//
#include <hip/hip_runtime.h>
#include <hip/hip_bf16.h>
#include <stdint.h>

// LSTM forward, B=64 T=512 D=512 H=512, return_sequences.
// Persistent kernel: 4 batch-groups x 32 column-slices = 128 blocks (1/CU,
// 132 KB LDS each). Weights packed in LDS in MFMA-frag order (fence-immune).
// Sync: relaxed spin on flags + single acquire fence (wave 0 only), release
// store to publish. h carried as bf16 hi+lo pair; fp32 accumulate everywhere.

#define Bdim 64
#define Tdim 512
#define Ddim 512
#define Hdim 512
#define G4H  2048

#define NG 4    // batch groups (16 rows each)
#define NS 32   // column slices per group (16 h-cols each)

typedef __bf16 bf16_t;
typedef __bf16 bf16x8 __attribute__((ext_vector_type(8)));
typedef float  f32x4  __attribute__((ext_vector_type(4)));

__device__ __forceinline__ float sigmoid_f(float x) {
  return 1.0f / (1.0f + __expf(-x));
}
__device__ __forceinline__ float tanh_f(float x) {
  return 1.0f - 2.0f / (__expf(2.0f * x) + 1.0f);  // stable both tails
}

// src [512][2048] fp32  ->  dst [2048][512] bf16 (transposed)
__global__ void transpose_bf16_512x2048(const float* __restrict__ src,
                                        bf16_t* __restrict__ dst) {
  __shared__ bf16_t tile[64][72];
  int c0 = blockIdx.x * 64;
  int r0 = blockIdx.y * 64;
  int tx = threadIdx.x & 63;
  int ty = threadIdx.x >> 6;
#pragma unroll
  for (int i = 0; i < 64; i += 4)
    tile[ty + i][tx] = (bf16_t)src[(size_t)(r0 + ty + i) * G4H + c0 + tx];
  __syncthreads();
#pragma unroll
  for (int i = 0; i < 64; i += 4)
    dst[(size_t)(c0 + ty + i) * Ddim + r0 + tx] = tile[tx][ty + i];
}

// fp32 -> bf16 elementwise (x pre-conversion), 8 elems/thread
__global__ void cast_bf16(const float* __restrict__ in, bf16_t* __restrict__ out) {
  size_t i = ((size_t)blockIdx.x * blockDim.x + threadIdx.x) * 8;
  f32x4 a = *(const f32x4*)(in + i);
  f32x4 b = *(const f32x4*)(in + i + 4);
  bf16x8 v;
#pragma unroll
  for (int j = 0; j < 4; ++j) { v[j] = (bf16_t)a[j]; v[j + 4] = (bf16_t)b[j]; }
  *(bf16x8*)(out + i) = v;
}

__launch_bounds__(256, 1)
__global__ void lstm_fused(const bf16_t* __restrict__ xb,   // [B][T][D] bf16
                           const bf16_t* __restrict__ Wt,   // [2048][512] bf16
                           const bf16_t* __restrict__ Ut,   // [2048][512] bf16
                           const float* __restrict__ bias,  // [2048]
                           float* __restrict__ out,         // [B][T][H] fp32
                           bf16_t* __restrict__ hbuf,       // [2 par][2 hilo][B][H]
                           unsigned* __restrict__ flags) {  // [NG*NS] stride 32
  extern __shared__ char smem[];
  bf16_t* LW = (bf16_t*)smem;                    // [4][16][64][8] frag order
  bf16_t* LU = LW + 4 * 16 * 64 * 8;             // same
  float*  EX = (float*)(smem + 2 * 65536);       // [4][16][17] gate exchange

  const int blk  = blockIdx.x;
  const int g    = blk >> 5;      // batch group
  const int s    = blk & 31;      // column slice
  const int wv   = threadIdx.x >> 6;   // wave = gate
  const int lane = threadIdx.x & 63;
  const int l15  = lane & 15;
  const int l4   = lane >> 4;
  const int b0   = g * 16;
  const int hc0  = s * 16;

  // ---- pack weight slices into LDS in MFMA B-frag order (wave wv = gate wv)
  {
    const bf16_t* wsrc = Wt + (size_t)(wv * Hdim + hc0 + l15) * Ddim + l4 * 8;
    const bf16_t* usrc = Ut + (size_t)(wv * Hdim + hc0 + l15) * Ddim + l4 * 8;
    bf16_t* lw = LW + (size_t)wv * 16 * 64 * 8 + lane * 8;
    bf16_t* lu = LU + (size_t)wv * 16 * 64 * 8 + lane * 8;
#pragma unroll
    for (int kk = 0; kk < 16; ++kk) {
      *(bf16x8*)(lw + kk * 64 * 8) = *(const bf16x8*)(wsrc + kk * 32);
      *(bf16x8*)(lu + kk * 64 * 8) = *(const bf16x8*)(usrc + kk * 32);
    }
  }
  __syncthreads();

  const float bg = bias[wv * Hdim + hc0 + l15];
  const bf16_t* lwg = LW + (size_t)wv * 16 * 64 * 8 + lane * 8;
  const bf16_t* lug = LU + (size_t)wv * 16 * 64 * 8 + lane * 8;
  const bf16_t* xrow = xb + (size_t)(b0 + l15) * Tdim * Ddim + l4 * 8;

  // epilogue/update mapping: this thread owns element (row=l15, col=wv*4+l4)
  const int urow = l15;
  const int ucol = wv * 4 + l4;
  float cstate = 0.f;
  float* outp = out + (size_t)(b0 + urow) * Tdim * Hdim + hc0 + ucol;

  bool dead = false;

  for (int t = 0; t < Tdim; ++t) {
    // ---------- x_t @ W  (2 k-split accumulators; overlaps peer publish) ----
    f32x4 aW0 = {bg, bg, bg, bg};
    f32x4 aW1 = {0.f, 0.f, 0.f, 0.f};
    const bf16_t* xp = xrow + (size_t)t * Ddim;
#pragma unroll
    for (int kk = 0; kk < 8; ++kk) {
      bf16x8 a0 = *(const bf16x8*)(xp + kk * 32);
      bf16x8 a1 = *(const bf16x8*)(xp + (kk + 8) * 32);
      bf16x8 w0 = *(const bf16x8*)(lwg + kk * 512);
      bf16x8 w1 = *(const bf16x8*)(lwg + (kk + 8) * 512);
      aW0 = __builtin_amdgcn_mfma_f32_16x16x32_bf16(a0, w0, aW0, 0, 0, 0);
      aW1 = __builtin_amdgcn_mfma_f32_16x16x32_bf16(a1, w1, aW1, 0, 0, 0);
    }

    f32x4 aH0 = {0,0,0,0}, aH1 = {0,0,0,0}, aL0 = {0,0,0,0}, aL1 = {0,0,0,0};
    if (t > 0) {
      // ---- wait for all 32 slices of h_{t-1}: relaxed spin + ONE acquire ----
      if (wv == 0 && !dead) {
        const unsigned* fp = flags + (size_t)(g * NS + (lane & 31)) * 32;
        int guard = 0;
        for (;;) {
          unsigned v = __hip_atomic_load(fp, __ATOMIC_RELAXED,
                                         __HIP_MEMORY_SCOPE_AGENT);
          if (__all((int)(v >= (unsigned)t))) break;
          if (++guard > 4000000) { dead = true; break; }
        }
        __builtin_amdgcn_fence(__ATOMIC_ACQUIRE, "agent");
      }
      __syncthreads();

      // ---------- h_{t-1} @ U  (hi/lo x k-split = 4 independent chains) ----
      const bf16_t* hb  = hbuf + (size_t)(((t - 1) & 1) * 2) * Bdim * Hdim;
      const bf16_t* hhi = hb + (size_t)(b0 + l15) * Hdim + l4 * 8;
      const bf16_t* hlo = hhi + (size_t)Bdim * Hdim;
#pragma unroll
      for (int kk = 0; kk < 8; ++kk) {
        bf16x8 ah0 = *(const bf16x8*)(hhi + kk * 32);
        bf16x8 ah1 = *(const bf16x8*)(hhi + (kk + 8) * 32);
        bf16x8 al0 = *(const bf16x8*)(hlo + kk * 32);
        bf16x8 al1 = *(const bf16x8*)(hlo + (kk + 8) * 32);
        bf16x8 u0  = *(const bf16x8*)(lug + kk * 512);
        bf16x8 u1  = *(const bf16x8*)(lug + (kk + 8) * 512);
        aH0 = __builtin_amdgcn_mfma_f32_16x16x32_bf16(ah0, u0, aH0, 0, 0, 0);
        aH1 = __builtin_amdgcn_mfma_f32_16x16x32_bf16(ah1, u1, aH1, 0, 0, 0);
        aL0 = __builtin_amdgcn_mfma_f32_16x16x32_bf16(al0, u0, aL0, 0, 0, 0);
        aL1 = __builtin_amdgcn_mfma_f32_16x16x32_bf16(al1, u1, aL1, 0, 0, 0);
      }
    }

    // ---------- gate exchange through LDS ----------
    float* exw = EX + wv * 16 * 17;
#pragma unroll
    for (int r = 0; r < 4; ++r) {
      float z = aW0[r] + aW1[r] + aH0[r] + aH1[r] + aL0[r] + aL1[r];
      exw[(l4 * 4 + r) * 17 + l15] = z;   // EX[gate][batchrow][zcol]
    }
    __syncthreads();

    // ---------- per-element update (each thread owns one (row,col)) --------
    float zi = EX[0 * 272 + urow * 17 + ucol];
    float zf = EX[1 * 272 + urow * 17 + ucol];
    float zc = EX[2 * 272 + urow * 17 + ucol];
    float zo = EX[3 * 272 + urow * 17 + ucol];
    float ig = sigmoid_f(zi), fg = sigmoid_f(zf);
    float ct = tanh_f(zc),    og = sigmoid_f(zo);
    float cn = tanh_f(fg * cstate + ig * ct);  // module carries ACTIVATED cell
    cstate = cn;
    float h = og * cn;
    outp[(size_t)t * Hdim] = h;
    bf16_t hh = (bf16_t)h;
    bf16_t hl = (bf16_t)(h - (float)hh);
    bf16_t* hw = hbuf + (size_t)((t & 1) * 2) * Bdim * Hdim;
    hw[(size_t)(b0 + urow) * Hdim + hc0 + ucol] = hh;
    hw[(size_t)Bdim * Hdim + (size_t)(b0 + urow) * Hdim + hc0 + ucol] = hl;

    __syncthreads();  // drains vmem stores of all waves before the flag
    if (threadIdx.x == 0) {
      __hip_atomic_store(flags + (size_t)(g * NS + s) * 32, (unsigned)(t + 1),
                         __ATOMIC_RELEASE, __HIP_MEMORY_SCOPE_AGENT);
    }
  }
}

extern "C" void kernel_launch(void* const* d_in, const int* in_sizes, int n_in,
                              void* d_out, int out_size, void* d_ws, size_t ws_size,
                              hipStream_t stream) {
  const float* x    = (const float*)d_in[0];
  const float* W    = (const float*)d_in[1];
  const float* U    = (const float*)d_in[2];
  const float* bias = (const float*)d_in[3];
  float* out = (float*)d_out;

  unsigned char* ws = (unsigned char*)d_ws;
  // layout: flags 16 KB | hbuf 256 KB | Wt 2 MB | Ut 2 MB | xb 32 MB
  unsigned* flags = (unsigned*)ws;
  bf16_t* hbuf = (bf16_t*)(ws + 16384);
  bf16_t* Wt   = (bf16_t*)(ws + 16384 + 262144);
  bf16_t* Ut   = Wt + (size_t)G4H * Ddim;
  bf16_t* xb   = Ut + (size_t)G4H * Ddim;

  hipMemsetAsync(flags, 0, 16384, stream);

  cast_bf16<<<(Bdim * Tdim * Ddim) / 2048, 256, 0, stream>>>(x, xb);

  dim3 tgrid(G4H / 64, Ddim / 64);
  transpose_bf16_512x2048<<<tgrid, 256, 0, stream>>>(W, Wt);
  transpose_bf16_512x2048<<<tgrid, 256, 0, stream>>>(U, Ut);

  size_t lds_bytes = 2 * 65536 + 4 * 16 * 17 * sizeof(float);  // 135424
  lstm_fused<<<NG * NS, 256, lds_bytes, stream>>>(xb, Wt, Ut, bias, out, hbuf,
                                                  flags);
}

// Round 3
// 3593.586 us; speedup vs baseline: 3.4747x; 1.4088x over previous
//
#include <hip/hip_runtime.h>
#include <hip/hip_bf16.h>
#include <stdint.h>

// LSTM forward, B=64 T=512 D=512 H=512, return_sequences.
// Persistent kernel: 4 batch-groups x 32 column-slices = 128 blocks (1/CU,
// ~133 KB LDS each). Weights in LDS in MFMA-frag order. Cross-block h-state
// and flags NEVER touch L1/L2: all comm via sc0+sc1 (LLC-direct) asm
// loads/stores -> no buffer_wbl2 / buffer_inv in the hot loop.
// h carried as bf16 hi+lo pair; fp32 accumulate everywhere.

#define Bdim 64
#define Tdim 512
#define Ddim 512
#define Hdim 512
#define G4H  2048

#define NG 4    // batch groups (16 rows each)
#define NS 32   // column slices per group (16 h-cols each)

typedef __bf16 bf16_t;
typedef __bf16 bf16x8 __attribute__((ext_vector_type(8)));
typedef float  f32x4  __attribute__((ext_vector_type(4)));

union v128 { f32x4 f; bf16x8 h; };

__device__ __forceinline__ float sigmoid_f(float x) {
  return 1.0f / (1.0f + __expf(-x));
}
__device__ __forceinline__ float tanh_f(float x) {
  return 1.0f - 2.0f / (__expf(2.0f * x) + 1.0f);  // stable both tails
}

// LLC-direct (device-coherent) 16B load/store: bypass L1 and L2.
#define LLC_LOAD16(dst, addr)                                              \
  asm volatile("global_load_dwordx4 %0, %1, off sc0 sc1"                   \
               : "=v"(dst) : "v"(addr))
#define LLC_STORE16(addr, val)                                             \
  asm volatile("global_store_dwordx4 %0, %1, off sc0 sc1" ::"v"(addr),     \
               "v"(val)                                                    \
               : "memory")

// src [512][2048] fp32  ->  dst [2048][512] bf16 (transposed)
__global__ void transpose_bf16_512x2048(const float* __restrict__ src,
                                        bf16_t* __restrict__ dst) {
  __shared__ bf16_t tile[64][72];
  int c0 = blockIdx.x * 64;
  int r0 = blockIdx.y * 64;
  int tx = threadIdx.x & 63;
  int ty = threadIdx.x >> 6;
#pragma unroll
  for (int i = 0; i < 64; i += 4)
    tile[ty + i][tx] = (bf16_t)src[(size_t)(r0 + ty + i) * G4H + c0 + tx];
  __syncthreads();
#pragma unroll
  for (int i = 0; i < 64; i += 4)
    dst[(size_t)(c0 + ty + i) * Ddim + r0 + tx] = tile[tx][ty + i];
}

// fp32 -> bf16 elementwise (x pre-conversion), 8 elems/thread
__global__ void cast_bf16(const float* __restrict__ in, bf16_t* __restrict__ out) {
  size_t i = ((size_t)blockIdx.x * blockDim.x + threadIdx.x) * 8;
  f32x4 a = *(const f32x4*)(in + i);
  f32x4 b = *(const f32x4*)(in + i + 4);
  bf16x8 v;
#pragma unroll
  for (int j = 0; j < 4; ++j) { v[j] = (bf16_t)a[j]; v[j + 4] = (bf16_t)b[j]; }
  *(bf16x8*)(out + i) = v;
}

__launch_bounds__(256, 1)
__global__ void lstm_fused(const bf16_t* __restrict__ xb,   // [B][T][D] bf16
                           const bf16_t* __restrict__ Wt,   // [2048][512] bf16
                           const bf16_t* __restrict__ Ut,   // [2048][512] bf16
                           const float* __restrict__ bias,  // [2048]
                           float* __restrict__ out,         // [B][T][H] fp32
                           bf16_t* __restrict__ hbuf,       // [2 par][2 hilo][B][H]
                           unsigned* __restrict__ flags) {  // [NG*NS] stride 32
  extern __shared__ char smem[];
  bf16_t* LW = (bf16_t*)smem;                      // [4][16][64][8] frag order
  bf16_t* LU = LW + 4 * 16 * 64 * 8;               // same
  float*  EX = (float*)(smem + 2 * 65536);         // [4][16][17] gate exchange
  bf16_t* HEX = (bf16_t*)(smem + 2 * 65536 + 4352);  // [2][16][16] h hi/lo

  const int blk  = blockIdx.x;
  const int g    = blk >> 5;      // batch group
  const int s    = blk & 31;      // column slice
  const int wv   = threadIdx.x >> 6;   // wave = gate
  const int lane = threadIdx.x & 63;
  const int l15  = lane & 15;
  const int l4   = lane >> 4;
  const int b0   = g * 16;
  const int hc0  = s * 16;

  // ---- pack weight slices into LDS in MFMA B-frag order (wave wv = gate wv)
  {
    const bf16_t* wsrc = Wt + (size_t)(wv * Hdim + hc0 + l15) * Ddim + l4 * 8;
    const bf16_t* usrc = Ut + (size_t)(wv * Hdim + hc0 + l15) * Ddim + l4 * 8;
    bf16_t* lw = LW + (size_t)wv * 16 * 64 * 8 + lane * 8;
    bf16_t* lu = LU + (size_t)wv * 16 * 64 * 8 + lane * 8;
#pragma unroll
    for (int kk = 0; kk < 16; ++kk) {
      *(bf16x8*)(lw + kk * 64 * 8) = *(const bf16x8*)(wsrc + kk * 32);
      *(bf16x8*)(lu + kk * 64 * 8) = *(const bf16x8*)(usrc + kk * 32);
    }
  }
  __syncthreads();

  const float bg = bias[wv * Hdim + hc0 + l15];
  const bf16_t* lwg = LW + (size_t)wv * 16 * 64 * 8 + lane * 8;
  const bf16_t* lug = LU + (size_t)wv * 16 * 64 * 8 + lane * 8;
  const bf16_t* xrow = xb + (size_t)(b0 + l15) * Tdim * Ddim + l4 * 8;

  // epilogue/update mapping: this thread owns element (row=l15, col=wv*4+l4)
  const int urow = l15;
  const int ucol = wv * 4 + l4;
  float cstate = 0.f;
  float* outp = out + (size_t)(b0 + urow) * Tdim * Hdim + hc0 + ucol;

  // h read bases for both parities (this thread's A-frag position)
  const bf16_t* hrd0 = hbuf + (size_t)(b0 + l15) * Hdim + l4 * 8;
  const bf16_t* hrd1 = hrd0 + (size_t)2 * Bdim * Hdim;

  bool dead = false;

  for (int t = 0; t < Tdim; ++t) {
    // ---------- x_t @ W  (cached loads; overlaps peer publish) ----------
    f32x4 aW0 = {bg, bg, bg, bg};
    f32x4 aW1 = {0.f, 0.f, 0.f, 0.f};
    const bf16_t* xp = xrow + (size_t)t * Ddim;
#pragma unroll
    for (int kk = 0; kk < 8; ++kk) {
      bf16x8 a0 = *(const bf16x8*)(xp + kk * 32);
      bf16x8 a1 = *(const bf16x8*)(xp + (kk + 8) * 32);
      bf16x8 w0 = *(const bf16x8*)(lwg + kk * 512);
      bf16x8 w1 = *(const bf16x8*)(lwg + (kk + 8) * 512);
      aW0 = __builtin_amdgcn_mfma_f32_16x16x32_bf16(a0, w0, aW0, 0, 0, 0);
      aW1 = __builtin_amdgcn_mfma_f32_16x16x32_bf16(a1, w1, aW1, 0, 0, 0);
    }

    f32x4 aH0 = {0,0,0,0}, aH1 = {0,0,0,0}, aL0 = {0,0,0,0}, aL1 = {0,0,0,0};
    if (t > 0) {
      // ---- wait for all 32 slices of h_{t-1}: LLC-direct spin, no fences ----
      if (wv == 0 && !dead) {
        const unsigned* fp = flags + (size_t)(g * NS + (lane & 31)) * 32;
        int guard = 0;
        for (;;) {
          unsigned v;
          asm volatile(
              "global_load_dword %0, %1, off sc0 sc1\n\t"
              "s_waitcnt vmcnt(0)"
              : "=v"(v) : "v"(fp));
          if (__all((int)(v >= (unsigned)t))) break;
          if (++guard > 4000000) { dead = true; break; }
        }
      }
      __syncthreads();

      // ---------- h_{t-1} @ U: deep-staged LLC loads, then MFMA burst ----
      const bf16_t* hhi = ((t - 1) & 1) ? hrd1 : hrd0;
      const bf16_t* hlo = hhi + (size_t)Bdim * Hdim;
      v128 rh0[8], rh1[8], rl0[8], rl1[8];
#pragma unroll
      for (int kk = 0; kk < 8; ++kk) LLC_LOAD16(rh0[kk].f, hhi + kk * 32);
#pragma unroll
      for (int kk = 0; kk < 8; ++kk) LLC_LOAD16(rh1[kk].f, hhi + (kk + 8) * 32);
#pragma unroll
      for (int kk = 0; kk < 8; ++kk) LLC_LOAD16(rl0[kk].f, hlo + kk * 32);
#pragma unroll
      for (int kk = 0; kk < 8; ++kk) LLC_LOAD16(rl1[kk].f, hlo + (kk + 8) * 32);
      asm volatile("s_waitcnt vmcnt(0)" ::: "memory");
      __builtin_amdgcn_sched_barrier(0);
#pragma unroll
      for (int kk = 0; kk < 8; ++kk) {
        bf16x8 u0 = *(const bf16x8*)(lug + kk * 512);
        bf16x8 u1 = *(const bf16x8*)(lug + (kk + 8) * 512);
        aH0 = __builtin_amdgcn_mfma_f32_16x16x32_bf16(rh0[kk].h, u0, aH0, 0, 0, 0);
        aH1 = __builtin_amdgcn_mfma_f32_16x16x32_bf16(rh1[kk].h, u1, aH1, 0, 0, 0);
        aL0 = __builtin_amdgcn_mfma_f32_16x16x32_bf16(rl0[kk].h, u0, aL0, 0, 0, 0);
        aL1 = __builtin_amdgcn_mfma_f32_16x16x32_bf16(rl1[kk].h, u1, aL1, 0, 0, 0);
      }
    }

    // ---------- gate exchange through LDS ----------
    float* exw = EX + wv * 16 * 17;
#pragma unroll
    for (int r = 0; r < 4; ++r) {
      float z = aW0[r] + aW1[r] + aH0[r] + aH1[r] + aL0[r] + aL1[r];
      exw[(l4 * 4 + r) * 17 + l15] = z;   // EX[gate][batchrow][zcol]
    }
    __syncthreads();

    // ---------- per-element update ----------
    float zi = EX[0 * 272 + urow * 17 + ucol];
    float zf = EX[1 * 272 + urow * 17 + ucol];
    float zc = EX[2 * 272 + urow * 17 + ucol];
    float zo = EX[3 * 272 + urow * 17 + ucol];
    float ig = sigmoid_f(zi), fg = sigmoid_f(zf);
    float ct = tanh_f(zc),    og = sigmoid_f(zo);
    float cn = tanh_f(fg * cstate + ig * ct);  // module carries ACTIVATED cell
    cstate = cn;
    float h = og * cn;
    outp[(size_t)t * Hdim] = h;
    bf16_t hh = (bf16_t)h;
    bf16_t hl = (bf16_t)(h - (float)hh);
    HEX[urow * 16 + ucol] = hh;          // [0][row][col]
    HEX[256 + urow * 16 + ucol] = hl;    // [1][row][col]
    __syncthreads();

    // ---------- publish h slice (wave 0): coalesced LLC stores + flag ----
    if (wv == 0) {
      const int arr  = lane >> 5;        // 0=hi 1=lo
      const int row  = (lane >> 1) & 15; // batch row
      const int half = lane & 1;         // 8-col half
      f32x4 val = *(const f32x4*)(HEX + arr * 256 + row * 16 + half * 8);
      bf16_t* dst = hbuf + (size_t)(t & 1) * 2 * Bdim * Hdim +
                    (size_t)arr * Bdim * Hdim + (size_t)(b0 + row) * Hdim +
                    hc0 + half * 8;
      LLC_STORE16(dst, val);
      asm volatile("s_waitcnt vmcnt(0)" ::: "memory");
      if (lane == 0) {
        unsigned stamp = (unsigned)(t + 1);
        const unsigned* fsp = flags + (size_t)(g * NS + s) * 32;
        asm volatile("global_store_dword %0, %1, off sc0 sc1" ::"v"(fsp),
                     "v"(stamp)
                     : "memory");
      }
    }
  }
}

extern "C" void kernel_launch(void* const* d_in, const int* in_sizes, int n_in,
                              void* d_out, int out_size, void* d_ws, size_t ws_size,
                              hipStream_t stream) {
  const float* x    = (const float*)d_in[0];
  const float* W    = (const float*)d_in[1];
  const float* U    = (const float*)d_in[2];
  const float* bias = (const float*)d_in[3];
  float* out = (float*)d_out;

  unsigned char* ws = (unsigned char*)d_ws;
  // layout: flags 16 KB | hbuf 256 KB | Wt 2 MB | Ut 2 MB | xb 32 MB
  unsigned* flags = (unsigned*)ws;
  bf16_t* hbuf = (bf16_t*)(ws + 16384);
  bf16_t* Wt   = (bf16_t*)(ws + 16384 + 262144);
  bf16_t* Ut   = Wt + (size_t)G4H * Ddim;
  bf16_t* xb   = Ut + (size_t)G4H * Ddim;

  hipMemsetAsync(flags, 0, 16384, stream);

  cast_bf16<<<(Bdim * Tdim * Ddim) / 2048, 256, 0, stream>>>(x, xb);

  dim3 tgrid(G4H / 64, Ddim / 64);
  transpose_bf16_512x2048<<<tgrid, 256, 0, stream>>>(W, Wt);
  transpose_bf16_512x2048<<<tgrid, 256, 0, stream>>>(U, Ut);

  size_t lds_bytes = 2 * 65536 + 4352 + 1024;  // LW+LU | EX | HEX = 136448
  lstm_fused<<<NG * NS, 256, lds_bytes, stream>>>(xb, Wt, Ut, bias, out, hbuf,
                                                  flags);
}

// Round 6
// 1525.743 us; speedup vs baseline: 8.1839x; 2.3553x over previous
//
#include <hip/hip_runtime.h>
#include <hip/hip_bf16.h>
#include <stdint.h>

// LSTM forward, B=64 T=512 D=512 H=512, return_sequences.
// v6: MALL-scope comm (proven in r3) with FLAG-IN-DATA stamping.
// 128 blocks = 4 batch-groups x 32 col-slices. Waves split k (128 each):
// weights in VGPRs; each wave polls ONLY its 8 producer slices' h data.
// h published per-thread as u32 = bf16hi<<16 | bf16lo&0xFFF0 | stamp4
// (stamp=(t+1)&15). Consumers poll the data itself (sc0 sc1), per-word
// stamp check -> detect+fetch in one MALL round trip, no flags at all.
// x@W runs between poll-issue and poll-wait. fp32 accumulate everywhere.

#define Bdim 64
#define Tdim 512
#define Ddim 512
#define Hdim 512
#define G4H  2048
#define NG 4
#define NS 32
#define BH (Bdim * Hdim)  // u32 elems per parity plane

typedef __bf16 bf16_t;
typedef __bf16 bf16x8 __attribute__((ext_vector_type(8)));
typedef float  f32x4  __attribute__((ext_vector_type(4)));
typedef uint32_t u32x4 __attribute__((ext_vector_type(4)));
union pv128 { u32x4 u; f32x4 f; bf16x8 h; };
union bu16 { bf16_t b; unsigned short u; };

__device__ __forceinline__ float sigmoid_f(float x) {
  return 1.0f / (1.0f + __expf(-x));
}
__device__ __forceinline__ float tanh_f(float x) {
  return 1.0f - 2.0f / (__expf(2.0f * x) + 1.0f);  // stable both tails
}

// src [512][2048] fp32  ->  dst [2048][512] bf16 (transposed)
__global__ void transpose_bf16_512x2048(const float* __restrict__ src,
                                        bf16_t* __restrict__ dst) {
  __shared__ bf16_t tile[64][72];
  int c0 = blockIdx.x * 64;
  int r0 = blockIdx.y * 64;
  int tx = threadIdx.x & 63;
  int ty = threadIdx.x >> 6;
#pragma unroll
  for (int i = 0; i < 64; i += 4)
    tile[ty + i][tx] = (bf16_t)src[(size_t)(r0 + ty + i) * G4H + c0 + tx];
  __syncthreads();
#pragma unroll
  for (int i = 0; i < 64; i += 4)
    dst[(size_t)(c0 + ty + i) * Ddim + r0 + tx] = tile[tx][ty + i];
}

// fp32 -> bf16 elementwise (x pre-conversion), 8 elems/thread
__global__ void cast_bf16(const float* __restrict__ in, bf16_t* __restrict__ out) {
  size_t i = ((size_t)blockIdx.x * blockDim.x + threadIdx.x) * 8;
  f32x4 a = *(const f32x4*)(in + i);
  f32x4 b = *(const f32x4*)(in + i + 4);
  bf16x8 v;
#pragma unroll
  for (int j = 0; j < 4; ++j) { v[j] = (bf16_t)a[j]; v[j + 4] = (bf16_t)b[j]; }
  *(bf16x8*)(out + i) = v;
}

#define MFMA16(A, B, C) __builtin_amdgcn_mfma_f32_16x16x32_bf16(A, B, C, 0, 0, 0)

// 8 stamped h loads (2 per k-chunk), MALL-direct
#define ISSUE_POLL()                                                         \
  asm volatile(                                                              \
      "global_load_dwordx4 %0, %8, off sc0 sc1\n\t"                          \
      "global_load_dwordx4 %1, %8, off offset:16 sc0 sc1\n\t"                \
      "global_load_dwordx4 %2, %8, off offset:128 sc0 sc1\n\t"               \
      "global_load_dwordx4 %3, %8, off offset:144 sc0 sc1\n\t"               \
      "global_load_dwordx4 %4, %8, off offset:256 sc0 sc1\n\t"               \
      "global_load_dwordx4 %5, %8, off offset:272 sc0 sc1\n\t"               \
      "global_load_dwordx4 %6, %8, off offset:384 sc0 sc1\n\t"               \
      "global_load_dwordx4 %7, %8, off offset:400 sc0 sc1"                   \
      : "=v"(p0.f), "=v"(p1.f), "=v"(p2.f), "=v"(p3.f), "=v"(p4.f),          \
        "=v"(p5.f), "=v"(p6.f), "=v"(p7.f)                                   \
      : "v"(hb)                                                              \
      : "memory")

#define CHECK(P)                                                             \
  do {                                                                       \
    bad |= (P.u[0] ^ st) & 15u;                                              \
    bad |= (P.u[1] ^ st) & 15u;                                              \
    bad |= (P.u[2] ^ st) & 15u;                                              \
    bad |= (P.u[3] ^ st) & 15u;                                              \
  } while (0)

// unpack chunk c (8 u32 -> hi/lo bf16x8) and run 8 MFMAs
#define HU(PA, PB, c)                                                        \
  do {                                                                       \
    pv128 hi_, lo_;                                                          \
    hi_.u[0] = (PA.u[0] >> 16) | (PA.u[1] & 0xFFFF0000u);                    \
    hi_.u[1] = (PA.u[2] >> 16) | (PA.u[3] & 0xFFFF0000u);                    \
    hi_.u[2] = (PB.u[0] >> 16) | (PB.u[1] & 0xFFFF0000u);                    \
    hi_.u[3] = (PB.u[2] >> 16) | (PB.u[3] & 0xFFFF0000u);                    \
    lo_.u[0] = (PA.u[0] & 0xFFF0u) | ((PA.u[1] & 0xFFF0u) << 16);            \
    lo_.u[1] = (PA.u[2] & 0xFFF0u) | ((PA.u[3] & 0xFFF0u) << 16);            \
    lo_.u[2] = (PB.u[0] & 0xFFF0u) | ((PB.u[1] & 0xFFF0u) << 16);            \
    lo_.u[3] = (PB.u[2] & 0xFFF0u) | ((PB.u[3] & 0xFFF0u) << 16);            \
    a0 = MFMA16(hi_.h, Ur[0][c], a0);                                        \
    a1 = MFMA16(hi_.h, Ur[1][c], a1);                                        \
    a2 = MFMA16(hi_.h, Ur[2][c], a2);                                        \
    a3 = MFMA16(hi_.h, Ur[3][c], a3);                                        \
    a0 = MFMA16(lo_.h, Ur[0][c], a0);                                        \
    a1 = MFMA16(lo_.h, Ur[1][c], a1);                                        \
    a2 = MFMA16(lo_.h, Ur[2][c], a2);                                        \
    a3 = MFMA16(lo_.h, Ur[3][c], a3);                                        \
  } while (0)

__launch_bounds__(256, 1)
__global__ void lstm_fused(const bf16_t* __restrict__ xb,   // [B][T][D] bf16
                           const bf16_t* __restrict__ Wt,   // [2048][512] bf16
                           const bf16_t* __restrict__ Ut,   // [2048][512] bf16
                           const float* __restrict__ bias,  // [2048]
                           float* __restrict__ out,         // [B][T][H] fp32
                           uint32_t* __restrict__ hbuf) {   // [2 par][B][H] u32
  __shared__ float EX[4][4][16][17];  // [wave][gate][row][col]

  const int blk  = blockIdx.x;
  const int g    = blk >> 5;
  const int s    = blk & 31;
  const int wv   = threadIdx.x >> 6;
  const int lane = threadIdx.x & 63;
  const int l15  = lane & 15;
  const int l4   = lane >> 4;
  const int b0   = g * 16;
  const int hc0  = s * 16;
  const int k0   = wv * 128;

  // ---- weights into registers (MFMA B-frag order) ----
  bf16x8 Wr[4][4], Ur[4][4];
#pragma unroll
  for (int G = 0; G < 4; ++G) {
    const bf16_t* wsrc = Wt + (size_t)(G * Hdim + hc0 + l15) * Ddim + k0 + l4 * 8;
    const bf16_t* usrc = Ut + (size_t)(G * Hdim + hc0 + l15) * Ddim + k0 + l4 * 8;
#pragma unroll
    for (int c = 0; c < 4; ++c) {
      Wr[G][c] = *(const bf16x8*)(wsrc + c * 32);
      Ur[G][c] = *(const bf16x8*)(usrc + c * 32);
    }
  }

  const int urow = threadIdx.x >> 4;
  const int ucol = threadIdx.x & 15;
  float b4[4];
#pragma unroll
  for (int G = 0; G < 4; ++G) b4[G] = bias[G * Hdim + hc0 + ucol];
  float cstate = 0.f;
  float* outp = out + (size_t)(b0 + urow) * Tdim * Hdim + hc0 + ucol;
  uint32_t* hpub = hbuf + (size_t)(b0 + urow) * Hdim + hc0 + ucol;
  const uint32_t* hrd = hbuf + (size_t)(b0 + l15) * Hdim + k0 + l4 * 8;
  const bf16_t* xrow = xb + (size_t)(b0 + l15) * Tdim * Ddim + l4 * 8 + k0;

  // ---- prologue: x(0) into regs ----
  pv128 xr0, xr1, xr2, xr3;
  asm volatile(
      "global_load_dwordx4 %0, %4, off nt\n\t"
      "global_load_dwordx4 %1, %4, off offset:64 nt\n\t"
      "global_load_dwordx4 %2, %4, off offset:128 nt\n\t"
      "global_load_dwordx4 %3, %4, off offset:192 nt\n\t"
      "s_waitcnt vmcnt(0)"
      : "=v"(xr0.f), "=v"(xr1.f), "=v"(xr2.f), "=v"(xr3.f)
      : "v"(xrow) : "memory");
  __builtin_amdgcn_sched_barrier(0);

  bool dead = false;

  for (int t = 0; t < Tdim; ++t) {
    pv128 p0, p1, p2, p3, p4, p5, p6, p7;
    const uint32_t st = (uint32_t)t & 15u;  // stamp on h_{t-1}
    const uint32_t* hb = hrd + (((t - 1) & 1) ? BH : 0);

    // [P] issue stamped h polls; they fly during x@W
    if (t > 0 && !dead) {
      ISSUE_POLL();
      __builtin_amdgcn_sched_barrier(0);
    }

    // [A] x_t @ W (registers only)
    f32x4 a0 = {0, 0, 0, 0}, a1 = {0, 0, 0, 0}, a2 = {0, 0, 0, 0}, a3 = {0, 0, 0, 0};
#define XW(c, xv)                                                            \
    a0 = MFMA16(xv.h, Wr[0][c], a0);                                         \
    a1 = MFMA16(xv.h, Wr[1][c], a1);                                         \
    a2 = MFMA16(xv.h, Wr[2][c], a2);                                         \
    a3 = MFMA16(xv.h, Wr[3][c], a3);
    XW(0, xr0) XW(1, xr1) XW(2, xr2) XW(3, xr3)
#undef XW

    if (t > 0) {
      // [C] poll until all 32 words carry stamp t
      if (!dead) {
        int guard = 0;
        for (;;) {
          asm volatile("s_waitcnt vmcnt(0)" ::: "memory");
          __builtin_amdgcn_sched_barrier(0);
          uint32_t bad = 0;
          CHECK(p0); CHECK(p1); CHECK(p2); CHECK(p3);
          CHECK(p4); CHECK(p5); CHECK(p6); CHECK(p7);
          if (__all(bad == 0)) break;
          if (++guard > 200000) { dead = true; break; }
          ISSUE_POLL();
          __builtin_amdgcn_sched_barrier(0);
        }
      } else {
        p0.u = p1.u = p2.u = p3.u = p4.u = p5.u = p6.u = p7.u = (u32x4)(0u);
      }
      // [U] unpack + h @ U (hi + lo)
      HU(p0, p1, 0);
      HU(p2, p3, 1);
      HU(p4, p5, 2);
      HU(p6, p7, 3);
    }

    // [D] prefetch x(t+1)
    {
      const bf16_t* xp = xrow + (size_t)((t + 1 < Tdim) ? t + 1 : Tdim - 1) * Ddim;
      asm volatile(
          "global_load_dwordx4 %0, %4, off nt\n\t"
          "global_load_dwordx4 %1, %4, off offset:64 nt\n\t"
          "global_load_dwordx4 %2, %4, off offset:128 nt\n\t"
          "global_load_dwordx4 %3, %4, off offset:192 nt"
          : "=v"(xr0.f), "=v"(xr1.f), "=v"(xr2.f), "=v"(xr3.f)
          : "v"(xp) : "memory");
    }

    // [G] k-partial z -> LDS
#pragma unroll
    for (int G = 0; G < 4; ++G) {
      f32x4 av = (G == 0) ? a0 : (G == 1) ? a1 : (G == 2) ? a2 : a3;
#pragma unroll
      for (int r = 0; r < 4; ++r) EX[wv][G][l4 * 4 + r][l15] = av[r];
    }
    __syncthreads();

    // [H] per-element update + direct stamped publish
    float z0 = EX[0][0][urow][ucol] + EX[1][0][urow][ucol] +
               EX[2][0][urow][ucol] + EX[3][0][urow][ucol] + b4[0];
    float z1 = EX[0][1][urow][ucol] + EX[1][1][urow][ucol] +
               EX[2][1][urow][ucol] + EX[3][1][urow][ucol] + b4[1];
    float z2 = EX[0][2][urow][ucol] + EX[1][2][urow][ucol] +
               EX[2][2][urow][ucol] + EX[3][2][urow][ucol] + b4[2];
    float z3 = EX[0][3][urow][ucol] + EX[1][3][urow][ucol] +
               EX[2][3][urow][ucol] + EX[3][3][urow][ucol] + b4[3];
    float ig = sigmoid_f(z0), fg = sigmoid_f(z1);
    float ct = tanh_f(z2), og = sigmoid_f(z3);
    float cn = tanh_f(fg * cstate + ig * ct);  // module carries ACTIVATED cell
    cstate = cn;
    float h = og * cn;

    bu16 hh; hh.b = (bf16_t)h;
    bu16 hl; hl.b = (bf16_t)(h - (float)hh.b);
    uint32_t pubw = ((uint32_t)hh.u << 16) | ((uint32_t)hl.u & 0xFFF0u) |
                    ((uint32_t)(t + 1) & 15u);
    uint32_t* dst = hpub + ((t & 1) ? BH : 0);
    asm volatile("global_store_dword %0, %1, off sc0 sc1" ::"v"(dst), "v"(pubw)
                 : "memory");
    __builtin_nontemporal_store(h, outp + (size_t)t * Hdim);

    __syncthreads();  // EX WAR protection

    // [J] drain x prefetch (and stores) before next [A]
    asm volatile("s_waitcnt vmcnt(0)" ::: "memory");
    __builtin_amdgcn_sched_barrier(0);
  }
}

extern "C" void kernel_launch(void* const* d_in, const int* in_sizes, int n_in,
                              void* d_out, int out_size, void* d_ws, size_t ws_size,
                              hipStream_t stream) {
  const float* x    = (const float*)d_in[0];
  const float* W    = (const float*)d_in[1];
  const float* U    = (const float*)d_in[2];
  const float* bias = (const float*)d_in[3];
  float* out = (float*)d_out;

  unsigned char* ws = (unsigned char*)d_ws;
  // layout: hbuf 256 KB (memset each call) | Wt 2 MB | Ut 2 MB | xb 32 MB
  uint32_t* hbuf = (uint32_t*)ws;
  bf16_t* Wt = (bf16_t*)(ws + 262144);
  bf16_t* Ut = Wt + (size_t)G4H * Ddim;
  bf16_t* xb = Ut + (size_t)G4H * Ddim;

  hipMemsetAsync(hbuf, 0, 262144, stream);

  cast_bf16<<<(Bdim * Tdim * Ddim) / 2048, 256, 0, stream>>>(x, xb);

  dim3 tgrid(G4H / 64, Ddim / 64);
  transpose_bf16_512x2048<<<tgrid, 256, 0, stream>>>(W, Wt);
  transpose_bf16_512x2048<<<tgrid, 256, 0, stream>>>(U, Ut);

  lstm_fused<<<NG * NS, 256, 0, stream>>>(xb, Wt, Ut, bias, out, hbuf);
}